// Round 13
// baseline (166.446 us; speedup 1.0000x reference)
//
#include <hip/hip_runtime.h>
#include <hip/hip_bf16.h>

#define EPSF 1e-8f
#define GAINF 0.014731391274719739f   // 1/sqrt(512*9)

typedef __attribute__((ext_vector_type(8))) __bf16 bf16x8;
typedef __attribute__((ext_vector_type(4))) __bf16 bf16x4;
typedef __attribute__((ext_vector_type(16))) float f32x16;

// async 16B global->LDS DMA; LDS dest = wave-uniform base + lane*16
#define GLOAD_LDS16(gp, lp) __builtin_amdgcn_global_load_lds( \
    (const __attribute__((address_space(1))) unsigned int*)(gp), \
    (__attribute__((address_space(3))) unsigned int*)(lp), 16, 0, 0)

// ---------------- K1 (fused): pack_x + (prep_w + sigma) + border zero --------
// xs layout: [b][cb16][site1156][32ch] bf16   (site = y*34+x, padded 34x34)
// wbf layout: [t9][cb16][o512][32ch] bf16
// Exact round-5 kernel (best measured total, 161.5 us).
__global__ void k_prep(const float* __restrict__ x, const float* __restrict__ style,
                       const float* __restrict__ w,
                       __hip_bfloat16* __restrict__ wbf, __hip_bfloat16* __restrict__ xs,
                       float* __restrict__ esc) {
  int blk = blockIdx.x, tid = threadIdx.x;
  if (blk < 2048) {
    // pack: 64ch x 64px tile via LDS transpose
    __shared__ float tile[64][65];
    int b = blk >> 7, rem = blk & 127, ct = rem >> 4, pt = rem & 15;
    int p0 = pt * 64, c0 = ct * 64;
    int tx = tid & 63, ty = tid >> 6;
#pragma unroll
    for (int k = 0; k < 16; ++k) {
      int ci = ty + k * 4;
      tile[ci][tx] = x[((b * 512) + (c0 + ci)) * 1024 + p0 + tx];
    }
    __syncthreads();
    // write: thread = (ch-quad, px); 8B bf16x4 stores, 64B runs
    int tq = tid & 15, py = tid >> 4;  // tq: ch-quad 0..15, py: px 0..15
    int c = c0 + tq * 4;
    int cb = c >> 5, cw = c & 31;
    float st0 = style[b * 512 + c], st1 = style[b * 512 + c + 1];
    float st2 = style[b * 512 + c + 2], st3 = style[b * 512 + c + 3];
#pragma unroll
    for (int k = 0; k < 4; ++k) {
      int pl = py + k * 16;
      int p = p0 + pl;
      int y = p >> 5, xx = p & 31;
      int site = (y + 1) * 34 + (xx + 1);
      bf16x4 v;
      v[0] = (__bf16)(tile[tq * 4 + 0][pl] * st0);
      v[1] = (__bf16)(tile[tq * 4 + 1][pl] * st1);
      v[2] = (__bf16)(tile[tq * 4 + 2][pl] * st2);
      v[3] = (__bf16)(tile[tq * 4 + 3][pl] * st3);
      *reinterpret_cast<bf16x4*>(xs + (size_t)(((b * 16 + cb) * 1156 + site) * 32 + cw)) = v;
    }
  } else if (blk < 2560) {
    // weight + sigma fused: block = one o; threads cover i in 2 halves
    __shared__ float red[4][16];
    int o = blk - 2048;
    float pacc[16];
#pragma unroll
    for (int b = 0; b < 16; ++b) pacc[b] = 0.f;
#pragma unroll
    for (int half = 0; half < 2; ++half) {
      int i = tid + half * 256;
      const float* p = w + (size_t)(o * 512 + i) * 9;
      float s = 0.f;
#pragma unroll
      for (int t = 0; t < 9; ++t) {
        float v = p[t];
        s += v * v;
        wbf[(size_t)t * 262144 + (i >> 5) * 16384 + o * 32 + (i & 31)] = __float2bfloat16(v);
      }
#pragma unroll
      for (int b = 0; b < 16; ++b) {
        float st = style[b * 512 + i];
        pacc[b] += st * st * s;
      }
    }
#pragma unroll
    for (int b = 0; b < 16; ++b)
#pragma unroll
      for (int off = 32; off; off >>= 1) pacc[b] += __shfl_down(pacc[b], off);
    int lane = tid & 63, wv2 = tid >> 6;
    if (lane == 0)
#pragma unroll
      for (int b = 0; b < 16; ++b) red[wv2][b] = pacc[b];
    __syncthreads();
    if (tid < 16) {
      float s = red[0][tid] + red[1][tid] + red[2][tid] + red[3][tid];
      esc[tid * 512 + o] = GAINF * rsqrtf(s * (GAINF * GAINF) + EPSF);
    }
  } else {
    // zero border: block = (b, cb); 132 sites x 32ch
    int bb = blk - 2560;
    int b = bb >> 4, cb = bb & 15;
    for (int i2 = tid; i2 < 528; i2 += 256) {  // 132 sites x 4 chunks
      int sb = i2 >> 2, q = i2 & 3;
      int yp, xp;
      if (sb < 34) { yp = 0; xp = sb; }
      else if (sb < 68) { yp = 33; xp = sb - 34; }
      else { int t2 = sb - 68; yp = 1 + (t2 >> 1); xp = (t2 & 1) * 33; }
      float4 z = {0.f, 0.f, 0.f, 0.f};
      *reinterpret_cast<float4*>(xs + (size_t)(((b * 16 + cb) * 1156 + yp * 34 + xp) * 32 + q * 8)) = z;
    }
  }
}

// ---------------- K3: implicit-GEMM conv -------------------------------------
// v8 = champion v2 with ONE change: BK=64 (stage a PAIR of channel-blocks per
// LDS buffer) -> 8 barriers instead of 16. The 9-tap inner body is
// byte-identical to v2 (lever isolation); waves 0-1 stage pair-half 0,
// waves 2-3 half 1, reproducing the exact 816-chunk swizzled layout per half
// (per-wave chunk c = (wv&1)*408 + j*64 + lane). LDS 52 KB/block, 104 KB/CU
// at 2 blocks/CU. Residual theory: ~47k cyc/CU of barrier-epoch cost
// (vmcnt(0) drain + 8-wave convergence x16); halving barrier count halves it.
// Pre-commit: conv >= 73 us -> revert to champion, declare structure floor.
__global__ __launch_bounds__(256, 2) void k_conv(
    const __hip_bfloat16* __restrict__ wbf, const __hip_bfloat16* __restrict__ xs,
    const float* __restrict__ esc, float* __restrict__ out) {
  __shared__ __hip_bfloat16 ldsB[2 * 13056];  // 2 bufs x (2 cb x 204 sites x 32 ch)
  int g = blockIdx.x;
  int xcd = g & 7, sblk = g >> 3;            // 512 blocks: 64 per XCD
  int mg = sblk >> 4;                        // 0..3 (128-o group)
  int n = xcd * 16 + (sblk & 15);            // 0..127; each XCD owns 2 images
  int b = n >> 3, nt = n & 7;
  int row0 = nt * 4;                         // padded rows row0..row0+5
  int tid = threadIdx.x;
  int wv = tid >> 6, lane = tid & 63;
  int l31 = lane & 31, lhi = lane >> 5;
  int o_base = mg * 128 + wv * 32;           // this wave's 32-o tile

  // pair staging: 1632 chunks of 16B; waves 0-1 cover half 0 (cb=2p), waves
  // 2-3 half 1 (cb=2p+1). Per-wave 408 chunks = 6 full rounds + 24 lanes.
  // Within a half, chunk c = (wv&1)*408 + j*64 + lane -> same site/XOR-swizzle
  // mapping as v2's 816-chunk layout. LDS dest stays linear per wave.
  int roff[7];
#pragma unroll
  for (int j = 0; j < 7; ++j) {
    int c = (wv & 1) * 408 + j * 64 + lane;
    int site = c >> 2, q0 = c & 3;
    int qs = q0 ^ ((site >> 1) & 3);
    roff[j] = site * 32 + qs * 8;
  }

#define STAGE_PAIR(p) do { \
    const __hip_bfloat16* _g = xs + (size_t)((b * 16 + 2 * (p) + (wv >> 1)) * 1156 + row0 * 34) * 32; \
    __hip_bfloat16* _l = ldsB + ((p) & 1) * 13056 + wv * 3264 + lane * 8; \
    _Pragma("unroll") \
    for (int _j = 0; _j < 6; ++_j) GLOAD_LDS16(_g + roff[_j], _l + _j * 512); \
    if (lane < 24) GLOAD_LDS16(_g + roff[6], _l + 6 * 512); \
  } while (0)

  int wrow = (o_base + l31) * 32 + lhi * 8;
#define LOADA(dst, t_, cb_) do { \
    const __hip_bfloat16* _p = wbf + (size_t)(t_) * 262144 + (cb_) * 16384 + wrow; \
    dst[0] = *reinterpret_cast<const bf16x8*>(_p); \
    dst[1] = *reinterpret_cast<const bf16x8*>(_p + 16); \
  } while (0)

  f32x16 acc[4];
#pragma unroll
  for (int j = 0; j < 4; ++j)
#pragma unroll
    for (int e = 0; e < 16; ++e) acc[j][e] = 0.f;

  bf16x8 aC[2], aN[2];  // A frags [k2], current/next tap
  STAGE_PAIR(0);        // cb 0 and 1
  LOADA(aC, 0, 0);

  for (int cbp = 0; cbp < 8; ++cbp) {
    __syncthreads();                  // drains STAGE_PAIR(cbp) (issued one pass ago)
    if (cbp < 7) STAGE_PAIR(cbp + 1); // async into other buffer, in flight all pass
#pragma unroll
    for (int h = 0; h < 2; ++h) {
      const int cb = cbp * 2 + h;
      const __hip_bfloat16* lb = ldsB + (cbp & 1) * 13056 + h * 6528;
#pragma unroll
      for (int t = 0; t < 9; ++t) {
        const int dy = t / 3, dx = t - dy * 3;
        if (cb < 15 || t < 8) {       // prefetch next tap's A (1 tap ahead)
          int tn = (t == 8) ? 0 : t + 1;
          int cbn = (t == 8) ? cb + 1 : cb;
          LOADA(aN, tn, cbn);
        }
        int s[4], sw[4];
#pragma unroll
        for (int ns = 0; ns < 4; ++ns) {
          s[ns] = (ns + dy) * 34 + l31 + dx;
          sw[ns] = (s[ns] >> 1) & 3;
        }
#pragma unroll
        for (int k2 = 0; k2 < 2; ++k2) {
          int ko = (k2 << 1) | lhi;
          bf16x8 bf[4];
#pragma unroll
          for (int ns = 0; ns < 4; ++ns)
            bf[ns] = *reinterpret_cast<const bf16x8*>(&lb[(s[ns] * 4 + (ko ^ sw[ns])) * 8]);
#pragma unroll
          for (int ns = 0; ns < 4; ++ns)
            acc[ns] = __builtin_amdgcn_mfma_f32_32x32x16_bf16(aC[k2], bf[ns], acc[ns], 0, 0, 0);
        }
        aC[0] = aN[0];
        aC[1] = aN[1];
      }
    }
  }
  // epilogue: C/D layout col=lane&31, row=(reg&3)+8*(reg>>2)+4*(lane>>5)
  int pxb = nt * 128 + l31;
#pragma unroll
  for (int reg = 0; reg < 16; ++reg) {
    int o = o_base + (reg & 3) + ((reg >> 2) << 3) + (lhi << 2);
    float e = esc[(b << 9) + o];
#pragma unroll
    for (int ns = 0; ns < 4; ++ns)
      out[(size_t)((b << 9) + o) * 1024 + pxb + ns * 32] = acc[ns][reg] * e;
  }
#undef STAGE_PAIR
#undef LOADA
}

extern "C" void kernel_launch(void* const* d_in, const int* in_sizes, int n_in,
                              void* d_out, int out_size, void* d_ws, size_t ws_size,
                              hipStream_t stream) {
  const float* x = (const float*)d_in[0];      // [16,512,32,32]
  const float* style = (const float*)d_in[1];  // [16,512]
  const float* w = (const float*)d_in[2];      // [512,512,3,3]
  float* out = (float*)d_out;                  // [16,512,32,32]
  char* ws = (char*)d_ws;
  __hip_bfloat16* wbf = (__hip_bfloat16*)(ws);            // 9*16*512*32*2 = 4,718,592
  __hip_bfloat16* xs  = (__hip_bfloat16*)(ws + 4718592);  // 16*16*1156*32*2 = 18,939,904
  float* esc = (float*)(ws + 23658496);                   // 32,768

  hipLaunchKernelGGL(k_prep, dim3(2816), dim3(256), 0, stream, x, style, w, wbf, xs, esc);
  hipLaunchKernelGGL(k_conv, dim3(512), dim3(256), 0, stream, wbf, xs, esc, out);
}

// Round 14
// 160.040 us; speedup vs baseline: 1.0400x; 1.0400x over previous
//
#include <hip/hip_runtime.h>
#include <hip/hip_bf16.h>

#define EPSF 1e-8f
#define GAINF 0.014731391274719739f   // 1/sqrt(512*9)

typedef __attribute__((ext_vector_type(8))) __bf16 bf16x8;
typedef __attribute__((ext_vector_type(4))) __bf16 bf16x4;
typedef __attribute__((ext_vector_type(16))) float f32x16;

// async 16B global->LDS DMA; LDS dest = wave-uniform base + lane*16
#define GLOAD_LDS16(gp, lp) __builtin_amdgcn_global_load_lds( \
    (const __attribute__((address_space(1))) unsigned int*)(gp), \
    (__attribute__((address_space(3))) unsigned int*)(lp), 16, 0, 0)

// ---------------- K1 (fused): pack_x + (prep_w + sigma) + border zero --------
// xs layout: [b][cb16][site1156][32ch] bf16   (site = y*34+x, padded 34x34)
// wbf layout: [t9][cb16][o512][32ch] bf16
// Exact round-5 kernel (best measured total, 161.5 us).
__global__ void k_prep(const float* __restrict__ x, const float* __restrict__ style,
                       const float* __restrict__ w,
                       __hip_bfloat16* __restrict__ wbf, __hip_bfloat16* __restrict__ xs,
                       float* __restrict__ esc) {
  int blk = blockIdx.x, tid = threadIdx.x;
  if (blk < 2048) {
    // pack: 64ch x 64px tile via LDS transpose
    __shared__ float tile[64][65];
    int b = blk >> 7, rem = blk & 127, ct = rem >> 4, pt = rem & 15;
    int p0 = pt * 64, c0 = ct * 64;
    int tx = tid & 63, ty = tid >> 6;
#pragma unroll
    for (int k = 0; k < 16; ++k) {
      int ci = ty + k * 4;
      tile[ci][tx] = x[((b * 512) + (c0 + ci)) * 1024 + p0 + tx];
    }
    __syncthreads();
    // write: thread = (ch-quad, px); 8B bf16x4 stores, 64B runs
    int tq = tid & 15, py = tid >> 4;  // tq: ch-quad 0..15, py: px 0..15
    int c = c0 + tq * 4;
    int cb = c >> 5, cw = c & 31;
    float st0 = style[b * 512 + c], st1 = style[b * 512 + c + 1];
    float st2 = style[b * 512 + c + 2], st3 = style[b * 512 + c + 3];
#pragma unroll
    for (int k = 0; k < 4; ++k) {
      int pl = py + k * 16;
      int p = p0 + pl;
      int y = p >> 5, xx = p & 31;
      int site = (y + 1) * 34 + (xx + 1);
      bf16x4 v;
      v[0] = (__bf16)(tile[tq * 4 + 0][pl] * st0);
      v[1] = (__bf16)(tile[tq * 4 + 1][pl] * st1);
      v[2] = (__bf16)(tile[tq * 4 + 2][pl] * st2);
      v[3] = (__bf16)(tile[tq * 4 + 3][pl] * st3);
      *reinterpret_cast<bf16x4*>(xs + (size_t)(((b * 16 + cb) * 1156 + site) * 32 + cw)) = v;
    }
  } else if (blk < 2560) {
    // weight + sigma fused: block = one o; threads cover i in 2 halves
    __shared__ float red[4][16];
    int o = blk - 2048;
    float pacc[16];
#pragma unroll
    for (int b = 0; b < 16; ++b) pacc[b] = 0.f;
#pragma unroll
    for (int half = 0; half < 2; ++half) {
      int i = tid + half * 256;
      const float* p = w + (size_t)(o * 512 + i) * 9;
      float s = 0.f;
#pragma unroll
      for (int t = 0; t < 9; ++t) {
        float v = p[t];
        s += v * v;
        wbf[(size_t)t * 262144 + (i >> 5) * 16384 + o * 32 + (i & 31)] = __float2bfloat16(v);
      }
#pragma unroll
      for (int b = 0; b < 16; ++b) {
        float st = style[b * 512 + i];
        pacc[b] += st * st * s;
      }
    }
#pragma unroll
    for (int b = 0; b < 16; ++b)
#pragma unroll
      for (int off = 32; off; off >>= 1) pacc[b] += __shfl_down(pacc[b], off);
    int lane = tid & 63, wv2 = tid >> 6;
    if (lane == 0)
#pragma unroll
      for (int b = 0; b < 16; ++b) red[wv2][b] = pacc[b];
    __syncthreads();
    if (tid < 16) {
      float s = red[0][tid] + red[1][tid] + red[2][tid] + red[3][tid];
      esc[tid * 512 + o] = GAINF * rsqrtf(s * (GAINF * GAINF) + EPSF);
    }
  } else {
    // zero border: block = (b, cb); 132 sites x 32ch
    int bb = blk - 2560;
    int b = bb >> 4, cb = bb & 15;
    for (int i2 = tid; i2 < 528; i2 += 256) {  // 132 sites x 4 chunks
      int sb = i2 >> 2, q = i2 & 3;
      int yp, xp;
      if (sb < 34) { yp = 0; xp = sb; }
      else if (sb < 68) { yp = 33; xp = sb - 34; }
      else { int t2 = sb - 68; yp = 1 + (t2 >> 1); xp = (t2 & 1) * 33; }
      float4 z = {0.f, 0.f, 0.f, 0.f};
      *reinterpret_cast<float4*>(xs + (size_t)(((b * 16 + cb) * 1156 + yp * 34 + xp) * 32 + q * 8)) = z;
    }
  }
}

// ---------------- K3: implicit-GEMM conv (champion — FINAL) ------------------
// Block = 256 thr = 4 waves sharing ONE staged B tile (128px n-tile,
// double-buffered, 26 KB). Wave tile 32o x 128px, acc[4]. Grid 512 =
// 2 blocks/CU -> 2 waves/SIMD. Compiler-scheduled per-tap interleave.
// Complete lever ledger (r0-r13): occupancy 1->2 waves/SIMD = -17us (the win);
// asm counted-waits +17; 64px waves +31; dx-major dedup +18; q-major
// conflict-free (4.98M->0 conflicts) +6 (conflicts fully hidden); A-depth-3
// neutral; BK=64 (8 barriers) +12. 73.5us = 44% MfmaUtil = ~1050 TF effective
// (42% of dense peak). Remaining slack needs the full 8-phase counted-vmcnt
// rebuild whose partial forms regressed 3x here. DO NOT modify this schedule.
__global__ __launch_bounds__(256, 2) void k_conv(
    const __hip_bfloat16* __restrict__ wbf, const __hip_bfloat16* __restrict__ xs,
    const float* __restrict__ esc, float* __restrict__ out) {
  __shared__ __hip_bfloat16 ldsB[2 * 6528];  // 2 bufs x 204 sites x 32 ch
  int g = blockIdx.x;
  int xcd = g & 7, sblk = g >> 3;            // 512 blocks: 64 per XCD
  int mg = sblk >> 4;                        // 0..3 (128-o group)
  int n = xcd * 16 + (sblk & 15);            // 0..127; each XCD owns 2 images
  int b = n >> 3, nt = n & 7;
  int row0 = nt * 4;                         // padded rows row0..row0+5
  int tid = threadIdx.x;
  int wv = tid >> 6, lane = tid & 63;
  int l31 = lane & 31, lhi = lane >> 5;
  int o_base = mg * 128 + wv * 32;           // this wave's 32-o tile

  // staging: 816 chunks of 16B split 204/wave = 3 full rounds + 12 lanes
  // XOR swizzle on the global side (LDS dest must stay linear per wave)
  int roff[4];
#pragma unroll
  for (int j = 0; j < 4; ++j) {
    int idx = wv * 204 + j * 64 + lane;
    int site = idx >> 2, q0 = idx & 3;
    int qs = q0 ^ ((site >> 1) & 3);
    roff[j] = site * 32 + qs * 8;
  }

#define STAGE(cbv) do { \
    const __hip_bfloat16* _g = xs + (size_t)((b * 16 + (cbv)) * 1156 + row0 * 34) * 32; \
    __hip_bfloat16* _l = ldsB + ((cbv) & 1) * 6528 + wv * 1632 + lane * 8; \
    _Pragma("unroll") \
    for (int _j = 0; _j < 3; ++_j) GLOAD_LDS16(_g + roff[_j], _l + _j * 512); \
    if (lane < 12) GLOAD_LDS16(_g + roff[3], _l + 3 * 512); \
  } while (0)

  int wrow = (o_base + l31) * 32 + lhi * 8;
#define LOADA(dst, t_, cb_) do { \
    const __hip_bfloat16* _p = wbf + (size_t)(t_) * 262144 + (cb_) * 16384 + wrow; \
    dst[0] = *reinterpret_cast<const bf16x8*>(_p); \
    dst[1] = *reinterpret_cast<const bf16x8*>(_p + 16); \
  } while (0)

  f32x16 acc[4];
#pragma unroll
  for (int j = 0; j < 4; ++j)
#pragma unroll
    for (int e = 0; e < 16; ++e) acc[j][e] = 0.f;

  bf16x8 aC[2], aN[2];  // A frags [k2], current/next tap
  STAGE(0);
  LOADA(aC, 0, 0);

  for (int cb = 0; cb < 16; ++cb) {
    __syncthreads();              // drains stage(cb) (issued one full cb ago)
    if (cb < 15) STAGE(cb + 1);   // async into other buffer, in flight all cb
    const __hip_bfloat16* lb = ldsB + (cb & 1) * 6528;
#pragma unroll
    for (int t = 0; t < 9; ++t) {
      const int dy = t / 3, dx = t - dy * 3;
      if (cb < 15 || t < 8) {     // prefetch next tap's A (1 tap = 8 MFMAs ahead)
        int tn = (t == 8) ? 0 : t + 1;
        int cbn = (t == 8) ? cb + 1 : cb;
        LOADA(aN, tn, cbn);
      }
      int s[4], sw[4];
#pragma unroll
      for (int ns = 0; ns < 4; ++ns) {
        s[ns] = (ns + dy) * 34 + l31 + dx;
        sw[ns] = (s[ns] >> 1) & 3;
      }
#pragma unroll
      for (int k2 = 0; k2 < 2; ++k2) {
        int ko = (k2 << 1) | lhi;
        bf16x8 bf[4];
#pragma unroll
        for (int ns = 0; ns < 4; ++ns)
          bf[ns] = *reinterpret_cast<const bf16x8*>(&lb[(s[ns] * 4 + (ko ^ sw[ns])) * 8]);
#pragma unroll
        for (int ns = 0; ns < 4; ++ns)
          acc[ns] = __builtin_amdgcn_mfma_f32_32x32x16_bf16(aC[k2], bf[ns], acc[ns], 0, 0, 0);
      }
      aC[0] = aN[0];
      aC[1] = aN[1];
    }
  }
  // epilogue: C/D layout col=lane&31, row=(reg&3)+8*(reg>>2)+4*(lane>>5)
  int pxb = nt * 128 + l31;
#pragma unroll
  for (int reg = 0; reg < 16; ++reg) {
    int o = o_base + (reg & 3) + ((reg >> 2) << 3) + (lhi << 2);
    float e = esc[(b << 9) + o];
#pragma unroll
    for (int ns = 0; ns < 4; ++ns)
      out[(size_t)((b << 9) + o) * 1024 + pxb + ns * 32] = acc[ns][reg] * e;
  }
#undef STAGE
#undef LOADA
}

extern "C" void kernel_launch(void* const* d_in, const int* in_sizes, int n_in,
                              void* d_out, int out_size, void* d_ws, size_t ws_size,
                              hipStream_t stream) {
  const float* x = (const float*)d_in[0];      // [16,512,32,32]
  const float* style = (const float*)d_in[1];  // [16,512]
  const float* w = (const float*)d_in[2];      // [512,512,3,3]
  float* out = (float*)d_out;                  // [16,512,32,32]
  char* ws = (char*)d_ws;
  __hip_bfloat16* wbf = (__hip_bfloat16*)(ws);            // 9*16*512*32*2 = 4,718,592
  __hip_bfloat16* xs  = (__hip_bfloat16*)(ws + 4718592);  // 16*16*1156*32*2 = 18,939,904
  float* esc = (float*)(ws + 23658496);                   // 32,768

  hipLaunchKernelGGL(k_prep, dim3(2816), dim3(256), 0, stream, x, style, w, wbf, xs, esc);
  hipLaunchKernelGGL(k_conv, dim3(512), dim3(256), 0, stream, wbf, xs, esc, out);
}